// Round 2
// baseline (246.938 us; speedup 1.0000x reference)
//
#include <hip/hip_runtime.h>
#include <hip/hip_bf16.h>

// WitnessEncoder: B=8, N=2048, VOCAB=32000, EMBED=256, HIDDEN=512
// ALL float tensors are f32 on device (per reference dtypes); we down-convert to
// bf16 for MFMA and accumulate in f32.
// Algebraic collapse: witness[b,d] = (1/N) sum_m colsum[b,m] * hidden[b,m,d],
// colsum[b,m] = sum_n softplus( dot(h_n,h_m) * invn[n] * invn[m] )  -- sim never materialized.

typedef __bf16 bf16;
typedef __bf16 bf16x2 __attribute__((ext_vector_type(2)));
typedef __bf16 bf16x4 __attribute__((ext_vector_type(4)));
typedef __bf16 bf16x8 __attribute__((ext_vector_type(8)));
typedef float f32x4 __attribute__((ext_vector_type(4)));

#define MFMA_BF16(a, b, c) __builtin_amdgcn_mfma_f32_16x16x32_bf16((a), (b), (c), 0, 0, 0)

__device__ __forceinline__ void async_copy16(const void* gptr, void* ldsptr) {
  __builtin_amdgcn_global_load_lds(
      (const __attribute__((address_space(1))) void*)gptr,
      (__attribute__((address_space(3))) void*)ldsptr, 16, 0, 0);
}

// embeds_b[row, :] = (bf16) emb[tokens[row], :]   row in [0,16384), E=256
__global__ __launch_bounds__(256)
void gather_convert(const int* __restrict__ tokens, const float* __restrict__ emb,
                    bf16* __restrict__ out)
{
  const int tid = blockIdx.x * 256 + threadIdx.x;  // 0..1048575 (16384*64)
  const int row = tid >> 6;
  const int c4 = (tid & 63) * 4;
  const int tok = tokens[row];
  const f32x4 v = *(const f32x4*)&emb[(size_t)tok * 256 + c4];
  bf16x4 o;
  o[0] = (bf16)v[0]; o[1] = (bf16)v[1]; o[2] = (bf16)v[2]; o[3] = (bf16)v[3];
  *(bf16x4*)&out[(size_t)row * 256 + c4] = o;
}

__global__ __launch_bounds__(256)
void convert_f32_bf16(const float* __restrict__ in, bf16* __restrict__ out, int n4)
{
  const int tid = blockIdx.x * 256 + threadIdx.x;
  if (tid >= n4) return;
  const f32x4 v = *(const f32x4*)&in[(size_t)tid * 4];
  bf16x4 o;
  o[0] = (bf16)v[0]; o[1] = (bf16)v[1]; o[2] = (bf16)v[2]; o[3] = (bf16)v[3];
  *(bf16x4*)&out[(size_t)tid * 4] = o;
}

// C[m,n] = epi( sum_k A[m,k]*Bw[n,k] + bias[n] ); 128x128 tile, BK=64, 4 waves,
// 16x16x32 bf16 MFMA, global_load_lds width=16 (m97-verified structure).
template <bool RELU>
__global__ __launch_bounds__(256)
void gemm_bt(const bf16* __restrict__ A, const bf16* __restrict__ Bw,
             const float* __restrict__ bias, bf16* __restrict__ C, int N, int K)
{
  __shared__ __align__(16) bf16 As[128 * 64];
  __shared__ __align__(16) bf16 Bs[128 * 64];
  const int m0 = blockIdx.x * 128;
  const int n0 = blockIdx.y * 128;
  const int t = threadIdx.x;
  const int lane = t & 63;
  const int w = t >> 6;
  const int wm = w >> 1, wn = w & 1;
  const int lr = lane & 15;
  const int lq = lane >> 4;

  f32x4 acc[4][4];
#pragma unroll
  for (int i = 0; i < 4; ++i)
#pragma unroll
    for (int j = 0; j < 4; ++j)
      acc[i][j] = (f32x4){0.f, 0.f, 0.f, 0.f};

  for (int k0 = 0; k0 < K; k0 += 64) {
#pragma unroll
    for (int i = 0; i < 4; ++i) {
      const int c = t + 256 * i;      // lds byte addr = c*16: lane-linear per wave
      const int row = c >> 3;
      const int kk = (c & 7) * 8;
      async_copy16(A + (size_t)(m0 + row) * K + (k0 + kk), &As[c * 8]);
      async_copy16(Bw + (size_t)(n0 + row) * K + (k0 + kk), &Bs[c * 8]);
    }
    __syncthreads();
#pragma unroll
    for (int ks = 0; ks < 2; ++ks) {
      const int kof = ks * 32 + lq * 8;
      bf16x8 af[4], bfr[4];
#pragma unroll
      for (int i = 0; i < 4; ++i)
        af[i] = *(const bf16x8*)&As[(wm * 64 + i * 16 + lr) * 64 + kof];
#pragma unroll
      for (int j = 0; j < 4; ++j)
        bfr[j] = *(const bf16x8*)&Bs[(wn * 64 + j * 16 + lr) * 64 + kof];
#pragma unroll
      for (int i = 0; i < 4; ++i)
#pragma unroll
        for (int j = 0; j < 4; ++j)
          acc[i][j] = MFMA_BF16(af[i], bfr[j], acc[i][j]);
    }
    __syncthreads();
  }

  // C/D layout: col = lane&15, row = (lane>>4)*4 + r
#pragma unroll
  for (int j = 0; j < 4; ++j) {
    const int col = n0 + wn * 64 + j * 16 + lr;
    const float bv = bias[col];
#pragma unroll
    for (int i = 0; i < 4; ++i) {
      const int rbase = m0 + wm * 64 + i * 16 + lq * 4;
#pragma unroll
      for (int r = 0; r < 4; ++r) {
        float v = acc[i][j][r] + bv;
        if (RELU) v = fmaxf(v, 0.0f);
        C[(size_t)(rbase + r) * N + col] = (bf16)v;
      }
    }
  }
}

// invn[row] = 1 / max(||hidden[row,:]||, 1e-12)
__global__ __launch_bounds__(256)
void inv_norm(const bf16* __restrict__ hidden, float* __restrict__ invn)
{
  const int row = blockIdx.x;
  const int t = threadIdx.x;
  const bf16x2 p = ((const bf16x2*)(hidden + (size_t)row * 512))[t];
  const float v0 = (float)p[0], v1 = (float)p[1];
  float ss = v0 * v0 + v1 * v1;
#pragma unroll
  for (int off = 32; off > 0; off >>= 1) ss += __shfl_down(ss, off, 64);
  __shared__ float wsum[4];
  if ((t & 63) == 0) wsum[t >> 6] = ss;
  __syncthreads();
  if (t == 0) {
    const float tot = wsum[0] + wsum[1] + wsum[2] + wsum[3];
    invn[row] = rsqrtf(fmaxf(tot, 1e-24f));
  }
}

// colsum_part[sp][b][m] = sum over split's n of softplus(dot(h_n,h_m)*invn[n]*invn[m])
__global__ __launch_bounds__(256)
void sim_colsum(const bf16* __restrict__ hidden, const float* __restrict__ invn,
                float* __restrict__ colsum_part)
{
  __shared__ __align__(16) bf16 As[128 * 64];
  __shared__ __align__(16) bf16 Bs[128 * 64];
  __shared__ float colacc[2][128];
  const int mt = blockIdx.x;   // 0..15
  const int b  = blockIdx.y;   // 0..7
  const int sp = blockIdx.z;   // 0..3
  const bf16* base = hidden + (size_t)b * (2048 * 512);
  const float* invb = invn + (size_t)b * 2048;
  const int m0 = mt * 128;
  const int t = threadIdx.x, lane = t & 63, w = t >> 6;
  const int wm = w >> 1, wn = w & 1, lr = lane & 15, lq = lane >> 4;

  float csum[4] = {0.f, 0.f, 0.f, 0.f};

  for (int nt = 0; nt < 4; ++nt) {
    const int n0 = sp * 512 + nt * 128;
    f32x4 acc[4][4];
#pragma unroll
    for (int i = 0; i < 4; ++i)
#pragma unroll
      for (int j = 0; j < 4; ++j)
        acc[i][j] = (f32x4){0.f, 0.f, 0.f, 0.f};

    for (int k0 = 0; k0 < 512; k0 += 64) {
#pragma unroll
      for (int i = 0; i < 4; ++i) {
        const int c = t + 256 * i;
        const int row = c >> 3;
        const int kk = (c & 7) * 8;
        async_copy16(base + (size_t)(n0 + row) * 512 + (k0 + kk), &As[c * 8]);
        async_copy16(base + (size_t)(m0 + row) * 512 + (k0 + kk), &Bs[c * 8]);
      }
      __syncthreads();
#pragma unroll
      for (int ks = 0; ks < 2; ++ks) {
        const int kof = ks * 32 + lq * 8;
        bf16x8 af[4], bfr[4];
#pragma unroll
        for (int i = 0; i < 4; ++i)
          af[i] = *(const bf16x8*)&As[(wm * 64 + i * 16 + lr) * 64 + kof];
#pragma unroll
        for (int j = 0; j < 4; ++j)
          bfr[j] = *(const bf16x8*)&Bs[(wn * 64 + j * 16 + lr) * 64 + kof];
#pragma unroll
        for (int i = 0; i < 4; ++i)
#pragma unroll
          for (int j = 0; j < 4; ++j)
            acc[i][j] = MFMA_BF16(af[i], bfr[j], acc[i][j]);
      }
      __syncthreads();
    }
    // epilogue: scale by inv norms, softplus, per-column partial sum over rows(n)
    f32x4 rv[4];
#pragma unroll
    for (int i = 0; i < 4; ++i)
      rv[i] = *(const f32x4*)&invb[n0 + wm * 64 + i * 16 + lq * 4];
#pragma unroll
    for (int j = 0; j < 4; ++j) {
      const float cv = invb[m0 + wn * 64 + j * 16 + lr];
      float s = 0.f;
#pragma unroll
      for (int i = 0; i < 4; ++i)
#pragma unroll
        for (int r = 0; r < 4; ++r) {
          const float x = acc[i][j][r] * rv[i][r] * cv;   // |x| <= ~1
          s += __logf(1.0f + __expf(x));
        }
      csum[j] += s;
    }
  }
  // sum over lane-quads (rows sharing a column): lanes l, l^16, l^32, l^48
#pragma unroll
  for (int j = 0; j < 4; ++j) {
    float s = csum[j];
    s += __shfl_xor(s, 16, 64);
    s += __shfl_xor(s, 32, 64);
    if (lq == 0) colacc[wm][wn * 64 + j * 16 + lr] = s;
  }
  __syncthreads();
  if (t < 128) {
    const float v = colacc[0][t] + colacc[1][t];
    colsum_part[((size_t)sp * 8 + b) * 2048 + (m0 + t)] = v;
  }
}

// wit_part[ms][b][d] = sum_{m in chunk} (sum_p colsum_part[p][b][m]) * hidden[b,m,d]
__global__ __launch_bounds__(256)
void witness_partial(const float* __restrict__ colsum_part, const bf16* __restrict__ hidden,
                     float* __restrict__ wit_part)
{
  const int ms = blockIdx.x;   // 0..7
  const int dh = blockIdx.y;   // 0..1
  const int b  = blockIdx.z;   // 0..7
  const int t = threadIdx.x;
  const int d = dh * 256 + t;
  const bf16* hb = hidden + (size_t)b * (2048 * 512);
  const float* cp = colsum_part + (size_t)b * 2048;
  float acc = 0.f;
  const int mbeg = ms * 256;
#pragma unroll 4
  for (int m = mbeg; m < mbeg + 256; ++m) {
    const float cw = cp[m] + cp[8 * 2048 + m] + cp[16 * 2048 + m] + cp[24 * 2048 + m];
    acc += cw * (float)hb[(size_t)m * 512 + d];
  }
  wit_part[((size_t)ms * 8 + b) * 512 + d] = acc;
}

// out[b,g] = bp[g] + sum_d (witness[b,d]/2048) * Wp[g,d]   (f32 Wp, f32 out)
__global__ __launch_bounds__(512)
void final_proj(const float* __restrict__ wit_part, const float* __restrict__ Wp,
                const float* __restrict__ bpv, float* __restrict__ out)
{
  const int b = blockIdx.x;
  const int t = threadIdx.x;   // g, 0..511
  __shared__ float wit[512];
  float s = 0.f;
#pragma unroll
  for (int p = 0; p < 8; ++p) s += wit_part[((size_t)p * 8 + b) * 512 + t];
  wit[t] = s * (1.0f / 2048.0f);
  __syncthreads();
  const float* wrow = Wp + (size_t)t * 512;
  float acc = bpv[t];
  for (int d0 = 0; d0 < 512; d0 += 4) {
    const f32x4 v = *(const f32x4*)&wrow[d0];
#pragma unroll
    for (int u = 0; u < 4; ++u) acc += v[u] * wit[d0 + u];
  }
  out[(size_t)b * 512 + t] = acc;
}

extern "C" void kernel_launch(void* const* d_in, const int* in_sizes, int n_in,
                              void* d_out, int out_size, void* d_ws, size_t ws_size,
                              hipStream_t stream) {
  (void)in_sizes; (void)n_in; (void)out_size; (void)ws_size;
  const int*   tokens = (const int*)d_in[0];
  const float* emb    = (const float*)d_in[1];
  const float* W1     = (const float*)d_in[2];
  const float* b1     = (const float*)d_in[3];
  const float* W2     = (const float*)d_in[4];
  const float* b2     = (const float*)d_in[5];
  const float* Wp     = (const float*)d_in[6];
  const float* bp     = (const float*)d_in[7];
  float* out = (float*)d_out;

  char* w = (char*)d_ws;
  bf16*  embeds_b = (bf16*)(w);                               // 16384*256*2 = 8 MB
  bf16*  W1_b     = (bf16*)(w + (size_t) 8 * 1024 * 1024);    // 512*256*2 = 256 KB
  bf16*  W2_b     = (bf16*)(w + (size_t) 9 * 1024 * 1024);    // 512*512*2 = 512 KB
  bf16*  h_buf    = (bf16*)(w + (size_t)10 * 1024 * 1024);    // 16384*512*2 = 16 MB
  bf16*  hidden   = (bf16*)(w + (size_t)26 * 1024 * 1024);    // 16 MB
  float* invn     = (float*)(w + (size_t)42 * 1024 * 1024);   // 16384*4 = 64 KB
  float* colsum   = (float*)(w + (size_t)42 * 1024 * 1024 + 64 * 1024);   // 256 KB
  float* witp     = (float*)(w + (size_t)42 * 1024 * 1024 + 320 * 1024);  // 128 KB

  // 0) dtype conversions (f32 -> bf16)
  gather_convert<<<4096, 256, 0, stream>>>(tokens, emb, embeds_b);
  convert_f32_bf16<<<128, 256, 0, stream>>>(W1, W1_b, 512 * 256 / 4);
  convert_f32_bf16<<<256, 256, 0, stream>>>(W2, W2_b, 512 * 512 / 4);
  // 1) h = relu(embeds @ W1^T + b1)   [16384,512]
  gemm_bt<true ><<<dim3(128, 4), 256, 0, stream>>>(embeds_b, W1_b, b1, h_buf, 512, 256);
  // 2) hidden = h @ W2^T + b2          [16384,512]
  gemm_bt<false><<<dim3(128, 4), 256, 0, stream>>>(h_buf, W2_b, b2, hidden, 512, 512);
  // 3) inverse row norms
  inv_norm<<<16384, 256, 0, stream>>>(hidden, invn);
  // 4) colsum partials (flash-style, sim never materialized)
  sim_colsum<<<dim3(16, 8, 4), 256, 0, stream>>>(hidden, invn, colsum);
  // 5) witness partials
  witness_partial<<<dim3(8, 2, 8), 256, 0, stream>>>(colsum, hidden, witp);
  // 6) out = witness/2048 @ Wp^T + bp
  final_proj<<<8, 512, 0, stream>>>(witp, Wp, bp, out);
}

// Round 3
// 180.536 us; speedup vs baseline: 1.3678x; 1.3678x over previous
//
#include <hip/hip_runtime.h>
#include <hip/hip_bf16.h>

// WitnessEncoder: B=8, N=2048, VOCAB=32000, EMBED=256, HIDDEN=512
// f32 inputs -> bf16 MFMA with f32 accumulate.
// colsum[b,m] = sum_n softplus(sim[n,m]); sim symmetric -> upper-triangle tiles only:
//   off-diag tile (I,J): col-sums -> colsum[J-range], row-sums -> colsum[I-range].
// witness[b,d] = (1/N) sum_m colsum[b,m] * hidden[b,m,d]; sim never materialized.
// LDS k-chunk XOR swizzle breaks the 16-way ds_read_b128 bank aliasing.

typedef __bf16 bf16;
typedef __bf16 bf16x2 __attribute__((ext_vector_type(2)));
typedef __bf16 bf16x4 __attribute__((ext_vector_type(4)));
typedef __bf16 bf16x8 __attribute__((ext_vector_type(8)));
typedef float f32x4 __attribute__((ext_vector_type(4)));

#define MFMA_BF16(a, b, c) __builtin_amdgcn_mfma_f32_16x16x32_bf16((a), (b), (c), 0, 0, 0)

__device__ __forceinline__ void async_copy16(const void* gptr, void* ldsptr) {
  __builtin_amdgcn_global_load_lds(
      (const __attribute__((address_space(1))) void*)gptr,
      (__attribute__((address_space(3))) void*)ldsptr, 16, 0, 0);
}

// softplus(x) = x/2 + ln(2cosh(x/2)) ~= x/2 + ln2 + x^2/8 - x^4/192 + x^6/2880  (|x|<=1.2: err<1e-4)
__device__ __forceinline__ float softplus_poly(float x) {
  const float u = x * x;
  float p = fmaf(u, 3.472222e-4f, -5.208333e-3f);
  p = fmaf(p, u, 0.125f);
  return fmaf(x, 0.5f, 0.69314718f) + p * u;
}

// embeds_b[row,:] = (bf16) emb[tokens[row],:]
__global__ __launch_bounds__(256)
void gather_convert(const int* __restrict__ tokens, const float* __restrict__ emb,
                    bf16* __restrict__ out)
{
  const int tid = blockIdx.x * 256 + threadIdx.x;  // 16384*64
  const int row = tid >> 6;
  const int c4 = (tid & 63) * 4;
  const int tok = tokens[row];
  const f32x4 v = *(const f32x4*)&emb[(size_t)tok * 256 + c4];
  bf16x4 o;
  o[0] = (bf16)v[0]; o[1] = (bf16)v[1]; o[2] = (bf16)v[2]; o[3] = (bf16)v[3];
  *(bf16x4*)&out[(size_t)row * 256 + c4] = o;
}

// merged W1 (512x256) + W2 (512x512) f32->bf16
__global__ __launch_bounds__(256)
void convert_weights(const float* __restrict__ W1, const float* __restrict__ W2,
                     bf16* __restrict__ W1b, bf16* __restrict__ W2b)
{
  const int tid = blockIdx.x * 256 + threadIdx.x;  // 0..98303
  const float* src; bf16* dst; int idx;
  if (tid < 32768) { src = W1; dst = W1b; idx = tid; }
  else             { src = W2; dst = W2b; idx = tid - 32768; }
  const f32x4 v = *(const f32x4*)&src[(size_t)idx * 4];
  bf16x4 o;
  o[0] = (bf16)v[0]; o[1] = (bf16)v[1]; o[2] = (bf16)v[2]; o[3] = (bf16)v[3];
  *(bf16x4*)&dst[(size_t)idx * 4] = o;
}

// C[m,n] = epi( sum_k A[m,k]*Bw[n,k] + bias[n] ). 128x128 tile, BK=64, swizzled LDS.
// SQ: also atomically accumulate row sums-of-squares of C into sq[global row].
template <bool RELU, bool SQ>
__global__ __launch_bounds__(256)
void gemm_bt(const bf16* __restrict__ A, const bf16* __restrict__ Bw,
             const float* __restrict__ bias, bf16* __restrict__ C,
             float* __restrict__ sq, int N, int K)
{
  __shared__ __align__(16) bf16 As[128 * 64];
  __shared__ __align__(16) bf16 Bs[128 * 64];
  const int m0 = blockIdx.x * 128;
  const int n0 = blockIdx.y * 128;
  const int t = threadIdx.x;
  const int lane = t & 63;
  const int w = t >> 6;
  const int wm = w >> 1, wn = w & 1;
  const int lr = lane & 15;
  const int lq = lane >> 4;

  f32x4 acc[4][4];
#pragma unroll
  for (int i = 0; i < 4; ++i)
#pragma unroll
    for (int j = 0; j < 4; ++j)
      acc[i][j] = (f32x4){0.f, 0.f, 0.f, 0.f};

  for (int k0 = 0; k0 < K; k0 += 64) {
#pragma unroll
    for (int i = 0; i < 4; ++i) {
      const int c = t + 256 * i;                    // LDS chunk: byte addr c*16 (lane-linear)
      const int row = c >> 3;
      const int kk = ((c & 7) ^ (row & 7)) * 8;     // XOR swizzle (same 128B row segment)
      async_copy16(A + (size_t)(m0 + row) * K + (k0 + kk), &As[c * 8]);
      async_copy16(Bw + (size_t)(n0 + row) * K + (k0 + kk), &Bs[c * 8]);
    }
    __syncthreads();
#pragma unroll
    for (int ks = 0; ks < 2; ++ks) {
      const int swz = ((ks * 4 + lq) ^ (lr & 7)) * 8;   // (row&7)==(lr&7) for all frag rows
      bf16x8 af[4], bfr[4];
#pragma unroll
      for (int i = 0; i < 4; ++i)
        af[i] = *(const bf16x8*)&As[(wm * 64 + i * 16 + lr) * 64 + swz];
#pragma unroll
      for (int j = 0; j < 4; ++j)
        bfr[j] = *(const bf16x8*)&Bs[(wn * 64 + j * 16 + lr) * 64 + swz];
#pragma unroll
      for (int i = 0; i < 4; ++i)
#pragma unroll
        for (int j = 0; j < 4; ++j)
          acc[i][j] = MFMA_BF16(af[i], bfr[j], acc[i][j]);
    }
    __syncthreads();
  }

  // C/D layout: col = lane&15, row = (lane>>4)*4 + r
  float bv4[4];
#pragma unroll
  for (int j = 0; j < 4; ++j) {
    const int col = n0 + wn * 64 + j * 16 + lr;
    const float bv = bias[col];
    bv4[j] = bv;
#pragma unroll
    for (int i = 0; i < 4; ++i) {
      const int rbase = m0 + wm * 64 + i * 16 + lq * 4;
#pragma unroll
      for (int r = 0; r < 4; ++r) {
        float v = acc[i][j][r] + bv;
        if (RELU) v = fmaxf(v, 0.0f);
        C[(size_t)(rbase + r) * N + col] = (bf16)v;
      }
    }
  }
  if (SQ) {
    // per-row sum of squares over this block's 128 cols -> atomicAdd into sq[row]
#pragma unroll
    for (int i = 0; i < 4; ++i)
#pragma unroll
      for (int r = 0; r < 4; ++r) {
        float s2 = 0.f;
#pragma unroll
        for (int j = 0; j < 4; ++j) {
          const float v = acc[i][j][r] + bv4[j];
          s2 += v * v;
        }
        s2 += __shfl_xor(s2, 1, 64);
        s2 += __shfl_xor(s2, 2, 64);
        s2 += __shfl_xor(s2, 4, 64);
        s2 += __shfl_xor(s2, 8, 64);
        if (lr == 0)
          atomicAdd(&sq[m0 + wm * 64 + i * 16 + lq * 4 + r], s2);
      }
  }
}

__global__ __launch_bounds__(256)
void invn_finalize(const float* __restrict__ sq, float* __restrict__ invn)
{
  const int i = blockIdx.x * 256 + threadIdx.x;   // 16384
  invn[i] = rsqrtf(fmaxf(sq[i], 1e-24f));
}

// Upper-triangle tile (I,J): T[i,j]=softplus(dot(h_n,h_m)*invn[n]*invn[m]).
// col-sums -> atomic colsum[J-range]; if I<J also row-sums -> atomic colsum[I-range].
__global__ __launch_bounds__(256)
void sim_colsum(const bf16* __restrict__ hidden, const float* __restrict__ invn,
                float* __restrict__ colsum)
{
  __shared__ __align__(16) bf16 As[128 * 64];
  __shared__ __align__(16) bf16 Bs[128 * 64];
  __shared__ float colacc[2][128];
  __shared__ float rowacc[2][128];
  // decode triangular pair index p -> (I,J), I<=J, 16 tiles per side
  int I = 0, J;
  {
    int rem = blockIdx.x, width = 16;
    while (rem >= width) { rem -= width; ++I; --width; }
    J = I + rem;
  }
  const bool diag = (I == J);
  const int b = blockIdx.y;
  const bf16* base = hidden + (size_t)b * (2048 * 512);
  const float* invb = invn + (size_t)b * 2048;
  float* csb = colsum + (size_t)b * 2048;
  const int n0 = I * 128;   // A rows (sim rows)
  const int m0 = J * 128;   // B rows (sim cols)
  const int t = threadIdx.x, lane = t & 63, w = t >> 6;
  const int wm = w >> 1, wn = w & 1, lr = lane & 15, lq = lane >> 4;

  f32x4 acc[4][4];
#pragma unroll
  for (int i = 0; i < 4; ++i)
#pragma unroll
    for (int j = 0; j < 4; ++j)
      acc[i][j] = (f32x4){0.f, 0.f, 0.f, 0.f};

  for (int k0 = 0; k0 < 512; k0 += 64) {
#pragma unroll
    for (int i = 0; i < 4; ++i) {
      const int c = t + 256 * i;
      const int row = c >> 3;
      const int kk = ((c & 7) ^ (row & 7)) * 8;
      async_copy16(base + (size_t)(n0 + row) * 512 + (k0 + kk), &As[c * 8]);
      async_copy16(base + (size_t)(m0 + row) * 512 + (k0 + kk), &Bs[c * 8]);
    }
    __syncthreads();
#pragma unroll
    for (int ks = 0; ks < 2; ++ks) {
      const int swz = ((ks * 4 + lq) ^ (lr & 7)) * 8;
      bf16x8 af[4], bfr[4];
#pragma unroll
      for (int i = 0; i < 4; ++i)
        af[i] = *(const bf16x8*)&As[(wm * 64 + i * 16 + lr) * 64 + swz];
#pragma unroll
      for (int j = 0; j < 4; ++j)
        bfr[j] = *(const bf16x8*)&Bs[(wn * 64 + j * 16 + lr) * 64 + swz];
#pragma unroll
      for (int i = 0; i < 4; ++i)
#pragma unroll
        for (int j = 0; j < 4; ++j)
          acc[i][j] = MFMA_BF16(af[i], bfr[j], acc[i][j]);
    }
    __syncthreads();
  }

  // epilogue: scale, softplus(poly), col-sums + row-sums
  f32x4 rv[4];
#pragma unroll
  for (int i = 0; i < 4; ++i)
    rv[i] = *(const f32x4*)&invb[n0 + wm * 64 + i * 16 + lq * 4];
  float csum[4];
  float rsum[4][4];
#pragma unroll
  for (int j = 0; j < 4; ++j) csum[j] = 0.f;
#pragma unroll
  for (int i = 0; i < 4; ++i)
#pragma unroll
    for (int r = 0; r < 4; ++r) rsum[i][r] = 0.f;

#pragma unroll
  for (int j = 0; j < 4; ++j) {
    const float cv = invb[m0 + wn * 64 + j * 16 + lr];
#pragma unroll
    for (int i = 0; i < 4; ++i)
#pragma unroll
      for (int r = 0; r < 4; ++r) {
        const float x = acc[i][j][r] * rv[i][r] * cv;   // |x| <= ~1
        const float s = softplus_poly(x);
        csum[j] += s;
        rsum[i][r] += s;
      }
  }
  // column sums: reduce over lane-quads (rows): lanes l, l^16, l^32, l^48
#pragma unroll
  for (int j = 0; j < 4; ++j) {
    float s = csum[j];
    s += __shfl_xor(s, 16, 64);
    s += __shfl_xor(s, 32, 64);
    if (lq == 0) colacc[wm][wn * 64 + j * 16 + lr] = s;
  }
  // row sums: reduce over lr lanes (cols) within quad
  if (!diag) {
#pragma unroll
    for (int i = 0; i < 4; ++i)
#pragma unroll
      for (int r = 0; r < 4; ++r) {
        float s = rsum[i][r];
        s += __shfl_xor(s, 1, 64);
        s += __shfl_xor(s, 2, 64);
        s += __shfl_xor(s, 4, 64);
        s += __shfl_xor(s, 8, 64);
        if (lr == 0) rowacc[wn][wm * 64 + i * 16 + lq * 4 + r] = s;
      }
  }
  __syncthreads();
  if (t < 128) {
    atomicAdd(&csb[m0 + t], colacc[0][t] + colacc[1][t]);
  } else if (!diag) {
    const int rr = t - 128;
    atomicAdd(&csb[n0 + rr], rowacc[0][rr] + rowacc[1][rr]);
  }
}

// witness[b,d] += sum_{m in 64-chunk} colsum[b,m] * hidden[b,m,d]
__global__ __launch_bounds__(256)
void witness_partial(const float* __restrict__ colsum, const bf16* __restrict__ hidden,
                     float* __restrict__ witness)
{
  const int mc = blockIdx.x;   // 0..31
  const int dh = blockIdx.y;   // 0..1
  const int b  = blockIdx.z;   // 0..7
  const int t = threadIdx.x;
  const int d = dh * 256 + t;
  const bf16* hb = hidden + (size_t)b * (2048 * 512);
  const float* cp = colsum + (size_t)b * 2048;
  float acc = 0.f;
  const int mbeg = mc * 64;
#pragma unroll 4
  for (int m = mbeg; m < mbeg + 64; ++m)
    acc += cp[m] * (float)hb[(size_t)m * 512 + d];
  atomicAdd(&witness[(size_t)b * 512 + d], acc);
}

// out[b,g] = bp[g] + (1/2048) * dot(witness[b,:], Wp[g,:])
__global__ __launch_bounds__(64)
void final_proj(const float* __restrict__ witness, const float* __restrict__ Wp,
                const float* __restrict__ bpv, float* __restrict__ out)
{
  const int b = blockIdx.x >> 3;
  const int gc = blockIdx.x & 7;
  const int g = gc * 64 + threadIdx.x;
  __shared__ float wit[512];
#pragma unroll
  for (int u = 0; u < 8; ++u)
    wit[threadIdx.x * 8 + u] = witness[(size_t)b * 512 + threadIdx.x * 8 + u];
  __syncthreads();
  const float* wrow = Wp + (size_t)g * 512;
  float acc = 0.f;
  for (int d0 = 0; d0 < 512; d0 += 4) {
    const f32x4 v = *(const f32x4*)&wrow[d0];
#pragma unroll
    for (int u = 0; u < 4; ++u) acc += v[u] * wit[d0 + u];
  }
  out[(size_t)b * 512 + g] = bpv[g] + acc * (1.0f / 2048.0f);
}

extern "C" void kernel_launch(void* const* d_in, const int* in_sizes, int n_in,
                              void* d_out, int out_size, void* d_ws, size_t ws_size,
                              hipStream_t stream) {
  (void)in_sizes; (void)n_in; (void)out_size; (void)ws_size;
  const int*   tokens = (const int*)d_in[0];
  const float* emb    = (const float*)d_in[1];
  const float* W1     = (const float*)d_in[2];
  const float* b1     = (const float*)d_in[3];
  const float* W2     = (const float*)d_in[4];
  const float* b2     = (const float*)d_in[5];
  const float* Wp     = (const float*)d_in[6];
  const float* bp     = (const float*)d_in[7];
  float* out = (float*)d_out;

  char* w = (char*)d_ws;
  bf16*  embeds_b = (bf16*)(w);                               // 8 MB
  bf16*  W1_b     = (bf16*)(w + (size_t) 8 * 1024 * 1024);    // 256 KB
  bf16*  W2_b     = (bf16*)(w + (size_t) 9 * 1024 * 1024);    // 512 KB
  bf16*  h_buf    = (bf16*)(w + (size_t)10 * 1024 * 1024);    // 16 MB
  bf16*  hidden   = (bf16*)(w + (size_t)26 * 1024 * 1024);    // 16 MB
  char*  zbase    =        (w + (size_t)42 * 1024 * 1024);
  float* sq       = (float*)(zbase);                          // 64 KB  (memset 0)
  float* colsum   = (float*)(zbase + 64 * 1024);              // 64 KB  (memset 0)
  float* witness  = (float*)(zbase + 128 * 1024);             // 16 KB  (memset 0)
  float* invn     = (float*)(zbase + 144 * 1024);             // 64 KB

  hipMemsetAsync(zbase, 0, 144 * 1024, stream);
  gather_convert<<<4096, 256, 0, stream>>>(tokens, emb, embeds_b);
  convert_weights<<<384, 256, 0, stream>>>(W1, W2, W1_b, W2_b);
  // h = relu(embeds @ W1^T + b1)
  gemm_bt<true,  false><<<dim3(128, 4), 256, 0, stream>>>(embeds_b, W1_b, b1, h_buf, nullptr, 512, 256);
  // hidden = h @ W2^T + b2, fused ||row||^2 partials
  gemm_bt<false, true ><<<dim3(128, 4), 256, 0, stream>>>(h_buf, W2_b, b2, hidden, sq, 512, 512);
  invn_finalize<<<64, 256, 0, stream>>>(sq, invn);
  // colsum via symmetric upper-triangle tiles (136 pairs x 8 batches)
  sim_colsum<<<dim3(136, 8), 256, 0, stream>>>(hidden, invn, colsum);
  witness_partial<<<dim3(32, 2, 8), 256, 0, stream>>>(colsum, hidden, witness);
  final_proj<<<64, 64, 0, stream>>>(witness, Wp, bp, out);
}